// Round 10
// baseline (203.033 us; speedup 1.0000x reference)
//
#include <hip/hip_runtime.h>
#include <hip/hip_bf16.h>
#include <math.h>

using bf16 = __hip_bfloat16;
typedef __attribute__((ext_vector_type(8))) short short8;   // 8 bf16 = 4 VGPRs (MFMA A/B frag)
typedef __attribute__((ext_vector_type(4))) float floatx4;  // MFMA C/D frag

#define MFMA16(a, b, c) __builtin_amdgcn_mfma_f32_16x16x32_bf16((a), (b), (c), 0, 0, 0)

// async global->LDS, 16B/lane; LDS dest = wave-uniform base + lane*16 [m97]
__device__ __forceinline__ void gll16(const void* g, void* l) {
  __builtin_amdgcn_global_load_lds((__attribute__((address_space(1))) void*)(uintptr_t)g,
                                   (__attribute__((address_space(3))) void*)l, 16, 0, 0);
}
// Bank-conflict swizzle: lane L stages global col-group (L&3)^((L>>3)&3) into
// LDS slot L. Frag reads use xg = g ^ ((c>>1)&3): banks 16(c&1)+4xg = 2-way (free).

// ---------------------------------------------------------------------------
// Detect dtype (fp32 vs bf16) + cast bias. One block.
// ---------------------------------------------------------------------------
__global__ void detect_bias_k(const unsigned short* __restrict__ x,
                              const void* __restrict__ bsrc,
                              bf16* __restrict__ bdst, int* __restrict__ flag) {
  __shared__ int cnt;
  if (threadIdx.x == 0) cnt = 0;
  __syncthreads();
  int local = 0;
  for (int i = threadIdx.x; i < 8192; i += 256) {
    unsigned short v = x[2 * i];  // low half of float i if fp32
    if (((v >> 7) & 0xFF) == 0xFF) local++;
  }
  if (local) atomicAdd(&cnt, local);
  __syncthreads();
  int f = (cnt > 0) ? 1 : 0;
  if (threadIdx.x == 0) *flag = f;
  for (int i = threadIdx.x; i < 1024; i += 256)
    bdst[i] = f ? __float2bfloat16(((const float*)bsrc)[i]) : ((const bf16*)bsrc)[i];
}

// ---------------------------------------------------------------------------
// Fused prep: z<2 -> x cast halves; z=2..5 -> transpose Wq/Wk/Wv/Wp to bf16.
// grid (32,32,6), block (32,8).
// ---------------------------------------------------------------------------
__global__ __launch_bounds__(256) void prep_k(const void* __restrict__ xin,
                                              bf16* __restrict__ xb,
                                              const void* __restrict__ W0,
                                              const void* __restrict__ W1,
                                              const void* __restrict__ W2,
                                              const void* __restrict__ W3,
                                              bf16* __restrict__ Wt,
                                              bf16* __restrict__ Wpt,
                                              const int* __restrict__ flag) {
  bool f32 = (*flag != 0);
  int z = blockIdx.z;
  if (z < 2) {  // x cast
    int tid = threadIdx.y * 32 + threadIdx.x;
    int blockLin = z * 1024 + blockIdx.y * 32 + blockIdx.x;
    int idx = blockLin * 2048 + tid * 8;
    if (f32) {
      const float4* p = reinterpret_cast<const float4*>((const float*)xin + idx);
      float4 a = p[0], b = p[1];
      union { bf16 h[8]; uint4 u; } U;
      U.h[0] = __float2bfloat16(a.x); U.h[1] = __float2bfloat16(a.y);
      U.h[2] = __float2bfloat16(a.z); U.h[3] = __float2bfloat16(a.w);
      U.h[4] = __float2bfloat16(b.x); U.h[5] = __float2bfloat16(b.y);
      U.h[6] = __float2bfloat16(b.z); U.h[7] = __float2bfloat16(b.w);
      *reinterpret_cast<uint4*>(xb + idx) = U.u;
    } else {
      *reinterpret_cast<uint4*>(xb + idx) =
          *reinterpret_cast<const uint4*>((const bf16*)xin + idx);
    }
    return;
  }
  const void* src = (z == 2) ? W0 : (z == 3) ? W1 : (z == 4) ? W2 : W3;
  bf16* dst = (z == 5) ? Wpt : (Wt + (size_t)(z - 2) * 1024 * 1024);
  __shared__ float tsh[32][33];
  int tx = threadIdx.x, ty = threadIdx.y;
  int k0 = blockIdx.y * 32, n0 = blockIdx.x * 32;
  for (int i = 0; i < 4; i++) {
    size_t off = (size_t)(k0 + ty + i * 8) * 1024 + n0 + tx;
    tsh[ty + i * 8][tx] = f32 ? ((const float*)src)[off]
                              : __bfloat162float(((const bf16*)src)[off]);
  }
  __syncthreads();
  for (int i = 0; i < 4; i++)
    dst[(size_t)(n0 + ty + i * 8) * 1024 + k0 + tx] = __float2bfloat16(tsh[tx][ty + i * 8]);
}

// ---------------------------------------------------------------------------
// QKV GEMM: C = xb @ Wt^T. 128x128 tile, BK=64, swizzled staging.
// Blocks with n0 < 2048 write Q|K into QKV2 (ldc=2048).
// Blocks with n0 >= 2048 write V directly TRANSPOSED into VT[bh*64+d][2048].
// ---------------------------------------------------------------------------
__global__ __launch_bounds__(256) void gemm_qkv(const bf16* __restrict__ A, int lda,
                                                const bf16* __restrict__ Bt, int ldb,
                                                bf16* __restrict__ QKV2,
                                                bf16* __restrict__ VT, int K) {
  __shared__ bf16 As[2][128 * 32];  // [k-half][row][32]
  __shared__ bf16 Bs[2][128 * 32];
  int t = threadIdx.x;
  int w = t >> 6, lane = t & 63;
  int g = lane >> 4, c = lane & 15;
  int wm = (w >> 1) * 64, wn = (w & 1) * 64;
  int m0 = blockIdx.y * 128, n0 = blockIdx.x * 128;

  int sr = w * 32 + (lane >> 2);
  int scz = (((lane & 3) ^ ((lane >> 3) & 3)) * 8);  // swizzled source col
  const bf16* Ab = A + (size_t)(m0 + sr) * lda + scz;
  const bf16* Bb = Bt + (size_t)(n0 + sr) * ldb + scz;
  int lofs = (w * 32) * 32;
  int xg8 = (g ^ ((c >> 1) & 3)) * 8;  // swizzled frag-read col

  floatx4 acc[4][4] = {};

  for (int k0 = 0; k0 < K; k0 += 64) {
    __syncthreads();
#pragma unroll
    for (int h = 0; h < 2; h++) {
      gll16(Ab + k0 + h * 32, &As[h][lofs]);
      gll16(Ab + k0 + h * 32 + (size_t)16 * lda, &As[h][lofs + 16 * 32]);
      gll16(Bb + k0 + h * 32, &Bs[h][lofs]);
      gll16(Bb + k0 + h * 32 + (size_t)16 * ldb, &Bs[h][lofs + 16 * 32]);
    }
    __syncthreads();
#pragma unroll
    for (int h = 0; h < 2; h++) {
      short8 af[4], bf[4];
#pragma unroll
      for (int i = 0; i < 4; i++) {
        af[i] = *reinterpret_cast<const short8*>(&As[h][(wm + i * 16 + c) * 32 + xg8]);
        bf[i] = *reinterpret_cast<const short8*>(&Bs[h][(wn + i * 16 + c) * 32 + xg8]);
      }
#pragma unroll
      for (int i = 0; i < 4; i++)
#pragma unroll
        for (int j = 0; j < 4; j++) acc[i][j] = MFMA16(af[i], bf[j], acc[i][j]);
    }
  }

  bool vblock = (n0 >= 2048);
  int bb = m0 >> 11;  // batch index (uniform per block)
#pragma unroll
  for (int i = 0; i < 4; i++) {
    int rbase = m0 + wm + i * 16 + g * 4;
#pragma unroll
    for (int j = 0; j < 4; j++) {
      int col = n0 + wn + j * 16 + c;
      if (!vblock) {
#pragma unroll
        for (int r = 0; r < 4; r++)
          QKV2[(size_t)(rbase + r) * 2048 + col] = __float2bfloat16(acc[i][j][r]);
      } else {
        int dcol = col - 2048;
        int hh = dcol >> 6, dl = dcol & 63;
        int s = rbase & 2047;
        union { bf16 h4[4]; uint2 u; } P;
#pragma unroll
        for (int r = 0; r < 4; r++) P.h4[r] = __float2bfloat16(acc[i][j][r]);
        *reinterpret_cast<uint2*>(
            &VT[((size_t)((bb * 16 + hh) * 64 + dl)) * 2048 + s]) = P.u;
      }
    }
  }
}

// ---------------------------------------------------------------------------
// GEMM 128x64 tile, BK=64, swizzled — projection: out = A @ Wpt^T + bias.
// ---------------------------------------------------------------------------
__global__ __launch_bounds__(256) void gemm_bt64(const bf16* __restrict__ A, int lda,
                                                 const bf16* __restrict__ Bt, int ldb,
                                                 void* __restrict__ C, int ldc,
                                                 const bf16* __restrict__ bias, int K,
                                                 const int* __restrict__ outflag) {
  __shared__ bf16 As[2][128 * 32];
  __shared__ bf16 Bs[2][64 * 32];
  int t = threadIdx.x;
  int w = t >> 6, lane = t & 63;
  int g = lane >> 4, c = lane & 15;
  int wm = (w >> 1) * 64, wn = (w & 1) * 32;
  int m0 = blockIdx.y * 128, n0 = blockIdx.x * 64;

  int sr = (lane >> 2);
  int scz = (((lane & 3) ^ ((lane >> 3) & 3)) * 8);
  const bf16* Ab = A + (size_t)(m0 + w * 32 + sr) * lda + scz;
  const bf16* Bb = Bt + (size_t)(n0 + w * 16 + sr) * ldb + scz;
  int laofs = (w * 32) * 32;
  int lbofs = (w * 16) * 32;
  int xg8 = (g ^ ((c >> 1) & 3)) * 8;

  floatx4 acc[4][2] = {};

  for (int k0 = 0; k0 < K; k0 += 64) {
    __syncthreads();
#pragma unroll
    for (int h = 0; h < 2; h++) {
      gll16(Ab + k0 + h * 32, &As[h][laofs]);
      gll16(Ab + k0 + h * 32 + (size_t)16 * lda, &As[h][laofs + 16 * 32]);
      gll16(Bb + k0 + h * 32, &Bs[h][lbofs]);
    }
    __syncthreads();
#pragma unroll
    for (int h = 0; h < 2; h++) {
      short8 af[4], bf[2];
#pragma unroll
      for (int i = 0; i < 4; i++)
        af[i] = *reinterpret_cast<const short8*>(&As[h][(wm + i * 16 + c) * 32 + xg8]);
#pragma unroll
      for (int j = 0; j < 2; j++)
        bf[j] = *reinterpret_cast<const short8*>(&Bs[h][(wn + j * 16 + c) * 32 + xg8]);
#pragma unroll
      for (int i = 0; i < 4; i++)
#pragma unroll
        for (int j = 0; j < 2; j++) acc[i][j] = MFMA16(af[i], bf[j], acc[i][j]);
    }
  }

  bool f32out = (outflag != nullptr) && (*outflag != 0);
#pragma unroll
  for (int i = 0; i < 4; i++) {
    int rbase = m0 + wm + i * 16 + g * 4;
#pragma unroll
    for (int j = 0; j < 2; j++) {
      int col = n0 + wn + j * 16 + c;
      float bv = bias ? __bfloat162float(bias[col]) : 0.f;
#pragma unroll
      for (int r = 0; r < 4; r++) {
        size_t off = (size_t)(rbase + r) * ldc + col;
        float v = acc[i][j][r] + bv;
        if (f32out) ((float*)C)[off] = v;
        else ((bf16*)C)[off] = __float2bfloat16(v);
      }
    }
  }
}

// ---------------------------------------------------------------------------
// Causal attention (round-8 structure + swizzled K/V staging/reads, LD=2048).
// 128 q-rows/block, 8 waves, double-buffered LDS K/V, one barrier per k-tile.
// Output in-place into the Q region of QKV2.
// ---------------------------------------------------------------------------
__global__ __launch_bounds__(512, 4) void attn_lds2(bf16* __restrict__ QKV,
                                                    const bf16* __restrict__ VT) {
  const int S = 2048, LD = 2048;
  __shared__ bf16 Ks[2][2][64 * 32];
  __shared__ bf16 Vs[2][2][64 * 32];
  __shared__ bf16 Pb[8][16 * 72];

  int t = threadIdx.x, w = t >> 6, lane = t & 63, g = lane >> 4, c = lane & 15;
  int bx = blockIdx.x, bh = blockIdx.y;
  int qt = (bh >= 16) ? bx : (15 - bx);
  int b = bh >> 4, h = bh & 15;
  int qbase = qt * 128;
  size_t rowb = (size_t)b * S;
  int hq = h * 64, hk = 1024 + h * 64;
  const bf16* Vt = VT + (size_t)bh * 64 * 2048;
  bf16* pb = Pb[w];

  int su = (w & 3) * 16 + (lane >> 2);
  int scz = (((lane & 3) ^ ((lane >> 3) & 3)) * 8);
  const bf16* Kg = &QKV[(rowb + su) * LD + hk + scz];
  const bf16* Vg = &Vt[(size_t)su * 2048 + scz];
  int sofs = ((w & 3) * 16) * 32;
  int xg8 = (g ^ ((c >> 1) & 3)) * 8;

  short8 qf[2];
#pragma unroll
  for (int hf = 0; hf < 2; hf++)
    qf[hf] = *reinterpret_cast<const short8*>(
        &QKV[(rowb + qbase + w * 16 + c) * LD + hq + hf * 32 + g * 8]);

  floatx4 o[4] = {};
  float l_r[4] = {};

  int nkt = 2 * qt + 2;
  if (w < 4) {
    gll16(Kg, &Ks[0][0][sofs]);
    gll16(Kg + 32, &Ks[0][1][sofs]);
  } else {
    gll16(Vg, &Vs[0][0][sofs]);
    gll16(Vg + 32, &Vs[0][1][sofs]);
  }

  for (int kt = 0; kt < nkt; kt++) {
    int kbase = kt * 64;
    int cur = kt & 1;
    __syncthreads();
    if (kt + 1 < nkt) {
      int nb = cur ^ 1;
      size_t kofs = (size_t)(kbase + 64);
      if (w < 4) {
        gll16(Kg + kofs * LD, &Ks[nb][0][sofs]);
        gll16(Kg + kofs * LD + 32, &Ks[nb][1][sofs]);
      } else {
        gll16(Vg + kofs, &Vs[nb][0][sofs]);
        gll16(Vg + kofs + 32, &Vs[nb][1][sofs]);
      }
    }

    short8 kf[4][2];
#pragma unroll
    for (int nt = 0; nt < 4; nt++)
#pragma unroll
      for (int hf = 0; hf < 2; hf++)
        kf[nt][hf] =
            *reinterpret_cast<const short8*>(&Ks[cur][hf][(nt * 16 + c) * 32 + xg8]);

    floatx4 s[4];
#pragma unroll
    for (int nt = 0; nt < 4; nt++) {
      floatx4 z = {};
      z = MFMA16(qf[0], kf[nt][0], z);
      z = MFMA16(qf[1], kf[nt][1], z);
      s[nt] = z;
    }

    int qrow = qbase + w * 16 + g * 4;
    bool diag = (kbase + 63 > qbase + w * 16);
#pragma unroll
    for (int nt = 0; nt < 4; nt++) {
      int kcol = kbase + nt * 16 + c;
#pragma unroll
      for (int r = 0; r < 4; r++) {
        float arg = fmaf(s[nt][r], 0.18033688f, -23.083120f);
        if (diag && (kcol > qrow + r)) arg = -1e30f;
        float p = exp2f(arg);
        l_r[r] += p;
        s[nt][r] = p;
      }
    }

    asm volatile("s_waitcnt lgkmcnt(0)" ::: "memory");
#pragma unroll
    for (int nt = 0; nt < 4; nt++)
#pragma unroll
      for (int r = 0; r < 4; r++)
        pb[(g * 4 + r) * 72 + nt * 16 + c] = __float2bfloat16(s[nt][r]);
    asm volatile("s_waitcnt lgkmcnt(0)" ::: "memory");
    short8 pf0 = *reinterpret_cast<const short8*>(&pb[c * 72 + g * 8]);
    short8 pf1 = *reinterpret_cast<const short8*>(&pb[c * 72 + 32 + g * 8]);

#pragma unroll
    for (int dt = 0; dt < 4; dt++) {
      short8 vf0 = *reinterpret_cast<const short8*>(&Vs[cur][0][(dt * 16 + c) * 32 + xg8]);
      short8 vf1 = *reinterpret_cast<const short8*>(&Vs[cur][1][(dt * 16 + c) * 32 + xg8]);
      o[dt] = MFMA16(pf0, vf0, o[dt]);
      o[dt] = MFMA16(pf1, vf1, o[dt]);
    }
  }

#pragma unroll
  for (int r = 0; r < 4; r++) {
    float v = l_r[r];
    v += __shfl_xor(v, 1); v += __shfl_xor(v, 2);
    v += __shfl_xor(v, 4); v += __shfl_xor(v, 8);
    l_r[r] = 1.0f / v;
  }

#pragma unroll
  for (int dt = 0; dt < 4; dt++)
#pragma unroll
    for (int r = 0; r < 4; r++) {
      float v = o[dt][r] * l_r[r];
      QKV[(rowb + qbase + w * 16 + g * 4 + r) * LD + hq + dt * 16 + c] =
          __float2bfloat16(v);
    }
}

// ---------------------------------------------------------------------------
extern "C" void kernel_launch(void* const* d_in, const int* in_sizes, int n_in,
                              void* d_out, int out_size, void* d_ws, size_t ws_size,
                              hipStream_t stream) {
  char* ws = (char*)d_ws;
  const size_t MB = 1024 * 1024;
  int* flag = (int*)ws;                       // 4 B
  bf16* bias = (bf16*)(ws + 4096);            // 2 KB
  bf16* xb = (bf16*)(ws + 1 * MB);            // [4096][1024]  8 MB
  bf16* Wt = (bf16*)(ws + 9 * MB);            // [3072][1024]  6 MB
  bf16* Wpt = (bf16*)(ws + 15 * MB);          // [1024][1024]  2 MB
  bf16* QKV2 = (bf16*)(ws + 17 * MB);         // [4096][2048] Q|K  16 MB
  bf16* VT = (bf16*)(ws + 33 * MB);           // [32*64][2048]      8 MB -> total 41 MB

  detect_bias_k<<<1, 256, 0, stream>>>((const unsigned short*)d_in[0], d_in[5], bias, flag);
  prep_k<<<dim3(32, 32, 6), dim3(32, 8), 0, stream>>>(d_in[0], xb, d_in[1], d_in[2],
                                                      d_in[3], d_in[4], Wt, Wpt, flag);

  // Q|K -> QKV2, V -> VT (transposed in epilogue) : M=4096, N=3072, K=1024
  gemm_qkv<<<dim3(24, 32), 256, 0, stream>>>(xb, 1024, Wt, 1024, QKV2, VT, 1024);
  // attention (in-place: output -> Q region of QKV2)
  attn_lds2<<<dim3(16, 32), 512, 0, stream>>>(QKV2, VT);
  // out = attn_out @ Wp + bp : M=4096, N=1024, K=1024 — 128x64 tiles, 512 blocks
  gemm_bt64<<<dim3(16, 32), 256, 0, stream>>>(QKV2, 2048, Wpt, 1024, d_out, 1024, bias,
                                              1024, flag);
}